// Round 12
// baseline (556.838 us; speedup 1.0000x reference)
//
#include <hip/hip_runtime.h>
#include <cstdint>
#include <cstddef>

// Problem constants
#define NB    8192      // batch
#define NP    4849      // params per item
#define NW    48        // target net width
#define NCH   38        // ceil(NP/128)
#define GY    16        // persistent-gemm grid y; each block does 128/GY = 8 M-tiles

// Tiled intermediate layout: addr(i, rp) = ((rp>>7)*NB + i)*128 + (rp&127)
typedef __attribute__((ext_vector_type(8))) _Float16 f16x8;
typedef __attribute__((ext_vector_type(4))) float f32x4;
typedef __attribute__((ext_vector_type(2))) float f32x2;

__device__ __forceinline__ const float* pptr(const float* Pp, int i, int rp) {
  return Pp + ((size_t)(rp >> 7) * NB + i) * 128 + (rp & 127);
}

__device__ __forceinline__ int invperm(int rp) {
  if (rp >= 96 && rp < 2400) {
    int t = rp - 96; int kb = t / 192; int rem = t - kb * 192;
    return 96 + (rem >> 2) * 48 + (kb * 4 + (rem & 3));
  }
  if (rp >= 2448 && rp < 4752) {
    int t = rp - 2448; int kb = t / 192; int rem = t - kb * 192;
    return 2448 + (rem >> 2) * 48 + (kb * 4 + (rem & 3));
  }
  return rp;
}

// ---------------------------------------------------------------------------
// Kernel 1: PERSISTENT split-fp16 MFMA GEMM (byte-identical to R10/R11).
// ~60 us real time = write roofline for the 163 MB intermediate; the rest of
// the apparent time is the harness's 159 MB d_ws re-poison inside each replay.
// ---------------------------------------------------------------------------
__global__ __launch_bounds__(256, 2) void hyper_gemm(
    const float* __restrict__ x, const float* __restrict__ c,
    const float* __restrict__ hw1, const float* __restrict__ hb1,
    const float* __restrict__ hw2, const float* __restrict__ hb2,
    float* __restrict__ Pp)
{
  const int t    = threadIdx.x;
  const int lane = t & 63;
  const int wv   = t >> 6;
  const int m16  = lane & 15;
  const int q    = lane >> 4;
  const int rp0  = blockIdx.x * 128;

  const float* wr[2];
  float bias[2];
  #pragma unroll
  for (int nt = 0; nt < 2; ++nt) {
    int rp = rp0 + wv * 32 + nt * 16 + m16;
    int r  = (rp < NP) ? invperm(rp) : 0;
    wr[nt]   = hw2 + (size_t)r * 96;
    bias[nt] = (rp < NP) ? hb2[r] : 0.f;
  }

  f16x8 bh[3][2], bl[3][2];
  #pragma unroll
  for (int ch = 0; ch < 3; ++ch) {
    const int k0 = ch * 32 + q * 8;
    #pragma unroll
    for (int nt = 0; nt < 2; ++nt) {
      float4 f0 = *(const float4*)(wr[nt] + k0);
      float4 f1 = *(const float4*)(wr[nt] + k0 + 4);
      float fv[8] = {f0.x,f0.y,f0.z,f0.w,f1.x,f1.y,f1.z,f1.w};
      #pragma unroll
      for (int e = 0; e < 8; ++e) {
        _Float16 hi = (_Float16)fv[e];
        float r = fv[e] - (float)hi;
        bh[ch][nt][e] = hi;
        bl[ch][nt][e] = (_Float16)r;
      }
    }
  }

  float* cbase = Pp + (size_t)blockIdx.x * NB * 128;

  for (int mtile = blockIdx.y; mtile < 128; mtile += GY) {
    const int i0 = mtile * 64;

    float xv[4], cv[4];
    #pragma unroll
    for (int mt = 0; mt < 4; ++mt) {
      int i = i0 + mt * 16 + m16;
      xv[mt] = x[i]; cv[mt] = c[i];
    }

    f32x4 acc[4][2];
    #pragma unroll
    for (int mt = 0; mt < 4; ++mt)
      #pragma unroll
      for (int nt = 0; nt < 2; ++nt)
        acc[mt][nt] = (f32x4){0.f, 0.f, 0.f, 0.f};

    #pragma unroll
    for (int ch = 0; ch < 3; ++ch) {
      const int k0 = ch * 32 + q * 8;

      float4 A0 = *(const float4*)(hw1 + 2 * k0);
      float4 A1 = *(const float4*)(hw1 + 2 * k0 + 4);
      float4 A2 = *(const float4*)(hw1 + 2 * k0 + 8);
      float4 A3 = *(const float4*)(hw1 + 2 * k0 + 12);
      float4 B0 = *(const float4*)(hb1 + k0);
      float4 B1 = *(const float4*)(hb1 + k0 + 4);
      float w0k[8] = {A0.x,A0.z,A1.x,A1.z,A2.x,A2.z,A3.x,A3.z};
      float w1k[8] = {A0.y,A0.w,A1.y,A1.w,A2.y,A2.w,A3.y,A3.w};
      float bk[8]  = {B0.x,B0.y,B0.z,B0.w,B1.x,B1.y,B1.z,B1.w};

      f16x8 ah[4], al[4];
      #pragma unroll
      for (int mt = 0; mt < 4; ++mt) {
        #pragma unroll
        for (int j = 0; j < 8; ++j) {
          float h = fmaf(xv[mt], w0k[j], fmaf(cv[mt], w1k[j], bk[j]));
          h = h > 0.f ? h : 0.f;
          _Float16 hi = (_Float16)h;
          float r = h - (float)hi;
          ah[mt][j] = hi;
          al[mt][j] = (_Float16)r;
        }
      }

      #pragma unroll
      for (int mt = 0; mt < 4; ++mt)
        #pragma unroll
        for (int nt = 0; nt < 2; ++nt) {
          acc[mt][nt] = __builtin_amdgcn_mfma_f32_16x16x32_f16(al[mt], bl[ch][nt], acc[mt][nt], 0, 0, 0);
          acc[mt][nt] = __builtin_amdgcn_mfma_f32_16x16x32_f16(ah[mt], bl[ch][nt], acc[mt][nt], 0, 0, 0);
          acc[mt][nt] = __builtin_amdgcn_mfma_f32_16x16x32_f16(al[mt], bh[ch][nt], acc[mt][nt], 0, 0, 0);
          acc[mt][nt] = __builtin_amdgcn_mfma_f32_16x16x32_f16(ah[mt], bh[ch][nt], acc[mt][nt], 0, 0, 0);
        }
    }

    #pragma unroll
    for (int nt = 0; nt < 2; ++nt) {
      int off = wv * 32 + nt * 16 + m16;
      if (rp0 + off < NP) {
        #pragma unroll
        for (int mt = 0; mt < 4; ++mt)
          #pragma unroll
          for (int r = 0; r < 4; ++r) {
            int i = i0 + mt * 16 + q * 4 + r;
            cbase[(size_t)i * 128 + off] = acc[mt][nt][r] + bias[nt];
          }
      }
    }
  }
}

// ---------------------------------------------------------------------------
// Kernel 2 (R12): per-item 20-step Adam — ONE WAVE PER WORKGROUP.
// R11 counters: occupancy pinned at 19% (~1.5 waves/SIMD) with 256-thread
// blocks across four rounds regardless of bounds — the 4-wave block is the
// packing obstacle. 64-thread blocks let the HW pack up to 16 workgroups/CU
// (VGPR 108 -> 4 waves/SIMD; LDS only 768 B/block). launch_bounds(64,4)
// caps regs at 128 >= 108: no R7-style scratch spill. Body identical to R11.
// ---------------------------------------------------------------------------
__device__ __forceinline__ float rcp_nr(float d) {
  float r = __builtin_amdgcn_rcpf(d);
  return fmaf(-d, r, 2.f) * r;
}

#define DPP_ADD(x, ctrl, rmask)                                               \
  (x) += __int_as_float(__builtin_amdgcn_update_dpp(                          \
      0, __float_as_int(x), (ctrl), (rmask), 0xf, false))

__global__ __launch_bounds__(64, 4) void adam_inner(
    const float* __restrict__ Pp, float* __restrict__ out)
{
  __shared__ __align__(16) float hd[2][96];   // [buf][h(48)|dh(48)]

  const int lane = threadIdx.x & 63;
  const int i    = blockIdx.x;
  const bool act = lane < NW;

  float* buf0 = &hd[0][0];
  float* buf1 = &hd[1][0];

  float w0  = act ? *pptr(Pp, i, lane)        : 0.f;
  float b0  = act ? *pptr(Pp, i, 48 + lane)   : 0.f;
  float b1v = act ? *pptr(Pp, i, 2400 + lane) : 0.f;
  float b2v = act ? *pptr(Pp, i, 4752 + lane) : 0.f;
  float w3  = act ? *pptr(Pp, i, 4800 + lane) : 0.f;

  f32x2 w1p[24], w2p[24];
  #pragma unroll
  for (int kb = 0; kb < 12; ++kb) {
    float4 q1 = *(const float4*)pptr(Pp, i, 96 + kb * 192 + lane * 4);
    w1p[2 * kb]     = (f32x2){q1.x, q1.y};
    w1p[2 * kb + 1] = (f32x2){q1.z, q1.w};
    float4 q2 = *(const float4*)pptr(Pp, i, 2448 + kb * 192 + lane * 4);
    w2p[2 * kb]     = (f32x2){q2.x, q2.y};
    w2p[2 * kb + 1] = (f32x2){q2.z, q2.w};
  }

  float y = 0.f, m = 0.f, v = 0.f;
  float b1t = 1.f, b2t = 1.f;

  #pragma unroll 1
  for (int t = 0; t < 20; ++t) {
    // ---- layer 0 (scalar input): lane j computes unit j ----
    float z  = fmaf(w0, y, b0);
    float e  = fminf(__expf(-z), 8.0e37f);
    float s  = rcp_nr(1.f + e);
    float h  = z * s;
    float dh = fmaf(z * s, 1.f - s, s) * w0;
    if (act) { buf0[lane] = h; buf0[48 + lane] = dh; }

    // ---- layer 1: prefetch broadcast reads, then independent pk chains ----
    float4 ph[12], pd[12];
    #pragma unroll
    for (int kk = 0; kk < 12; ++kk) {
      ph[kk] = *(const float4*)(buf0 + 4 * kk);
      pd[kk] = *(const float4*)(buf0 + 48 + 4 * kk);
    }
    {
      f32x2 zz[4] = {(f32x2){b1v, 0.f}, (f32x2){0.f, 0.f},
                     (f32x2){0.f, 0.f}, (f32x2){0.f, 0.f}};
      f32x2 dd[4] = {(f32x2){0.f, 0.f}, (f32x2){0.f, 0.f},
                     (f32x2){0.f, 0.f}, (f32x2){0.f, 0.f}};
      #pragma unroll
      for (int kk = 0; kk < 12; ++kk) {
        int c0 = (2 * kk) & 3, c1 = (2 * kk + 1) & 3;
        zz[c0] = __builtin_elementwise_fma(w1p[2 * kk],     (f32x2){ph[kk].x, ph[kk].y}, zz[c0]);
        zz[c1] = __builtin_elementwise_fma(w1p[2 * kk + 1], (f32x2){ph[kk].z, ph[kk].w}, zz[c1]);
        dd[c0] = __builtin_elementwise_fma(w1p[2 * kk],     (f32x2){pd[kk].x, pd[kk].y}, dd[c0]);
        dd[c1] = __builtin_elementwise_fma(w1p[2 * kk + 1], (f32x2){pd[kk].z, pd[kk].w}, dd[c1]);
      }
      f32x2 zs = (zz[0] + zz[1]) + (zz[2] + zz[3]);
      f32x2 ds = (dd[0] + dd[1]) + (dd[2] + dd[3]);
      float z1  = zs.x + zs.y;
      float dz1 = ds.x + ds.y;

      e  = fminf(__expf(-z1), 8.0e37f);
      s  = rcp_nr(1.f + e);
      h  = z1 * s;
      dh = fmaf(z1 * s, 1.f - s, s) * dz1;
    }
    if (act) { buf1[lane] = h; buf1[48 + lane] = dh; }

    // ---- layer 2 ----
    #pragma unroll
    for (int kk = 0; kk < 12; ++kk) {
      ph[kk] = *(const float4*)(buf1 + 4 * kk);
      pd[kk] = *(const float4*)(buf1 + 48 + 4 * kk);
    }
    {
      f32x2 zz[4] = {(f32x2){b2v, 0.f}, (f32x2){0.f, 0.f},
                     (f32x2){0.f, 0.f}, (f32x2){0.f, 0.f}};
      f32x2 dd[4] = {(f32x2){0.f, 0.f}, (f32x2){0.f, 0.f},
                     (f32x2){0.f, 0.f}, (f32x2){0.f, 0.f}};
      #pragma unroll
      for (int kk = 0; kk < 12; ++kk) {
        int c0 = (2 * kk) & 3, c1 = (2 * kk + 1) & 3;
        zz[c0] = __builtin_elementwise_fma(w2p[2 * kk],     (f32x2){ph[kk].x, ph[kk].y}, zz[c0]);
        zz[c1] = __builtin_elementwise_fma(w2p[2 * kk + 1], (f32x2){ph[kk].z, ph[kk].w}, zz[c1]);
        dd[c0] = __builtin_elementwise_fma(w2p[2 * kk],     (f32x2){pd[kk].x, pd[kk].y}, dd[c0]);
        dd[c1] = __builtin_elementwise_fma(w2p[2 * kk + 1], (f32x2){pd[kk].z, pd[kk].w}, dd[c1]);
      }
      f32x2 zs = (zz[0] + zz[1]) + (zz[2] + zz[3]);
      f32x2 ds = (dd[0] + dd[1]) + (dd[2] + dd[3]);
      float z2  = zs.x + zs.y;
      float dz2 = ds.x + ds.y;

      e  = fminf(__expf(-z2), 8.0e37f);
      s  = rcp_nr(1.f + e);
      dh = fmaf(z2 * s, 1.f - s, s) * dz2;
    }

    // ---- g = w3 . dh3 : DPP reduction (VALU pipe, no DS ops) ----
    float r = act ? w3 * dh : 0.f;
    DPP_ADD(r, 0x111, 0xf);   // row_shr:1
    DPP_ADD(r, 0x112, 0xf);   // row_shr:2
    DPP_ADD(r, 0x114, 0xf);   // row_shr:4
    DPP_ADD(r, 0x118, 0xf);   // row_shr:8  -> lane15 of each row = row sum
    DPP_ADD(r, 0x142, 0xa);   // row_bcast:15 into rows 1,3
    DPP_ADD(r, 0x143, 0xc);   // row_bcast:31 into rows 2,3 -> lane63 = total
    float g = __int_as_float(__builtin_amdgcn_readlane(__float_as_int(r), 63));

    // ---- Adam update (replicated per lane) ----
    m = fmaf(0.9f,   m, 0.1f   * g);
    v = fmaf(0.999f, v, 0.001f * g * g);
    b1t *= 0.9f; b2t *= 0.999f;
    float mh  = m * rcp_nr(1.f - b1t);
    float vh  = v * rcp_nr(1.f - b2t);
    float den = __builtin_amdgcn_sqrtf(vh) + 1e-8f;
    y -= 0.1f * mh * rcp_nr(den);
  }

  if (lane == 0) out[i] = y;
}

// ---------------------------------------------------------------------------
extern "C" void kernel_launch(void* const* d_in, const int* in_sizes, int n_in,
                              void* d_out, int out_size, void* d_ws, size_t ws_size,
                              hipStream_t stream) {
  const float* x   = (const float*)d_in[0];
  const float* c   = (const float*)d_in[1];
  const float* hw1 = (const float*)d_in[2];
  const float* hb1 = (const float*)d_in[3];
  const float* hw2 = (const float*)d_in[4];
  const float* hb2 = (const float*)d_in[5];
  float* Pp  = (float*)d_ws;   // NCH*NB*128*4 = 159,383,552 bytes
  float* out = (float*)d_out;

  dim3 gridB(NCH, GY);         // 38 x 16 persistent blocks
  hyper_gemm<<<gridB, dim3(256), 0, stream>>>(x, c, hw1, hb1, hw2, hb2, Pp);
  adam_inner<<<dim3(NB), dim3(64), 0, stream>>>(Pp, out);
}

// Round 13
// 237.728 us; speedup vs baseline: 2.3423x; 2.3423x over previous
//
#include <hip/hip_runtime.h>
#include <cstdint>
#include <cstddef>

// Problem constants
#define NB    8192      // batch
#define NP    4849      // params per item
#define NW    48        // target net width
#define NCH   38        // ceil(NP/128)
#define GY    16        // persistent-gemm grid y; each block does 128/GY = 8 M-tiles

// Tiled intermediate layout: addr(i, rp) = ((rp>>7)*NB + i)*128 + (rp&127)
typedef __attribute__((ext_vector_type(8))) _Float16 f16x8;
typedef __attribute__((ext_vector_type(4))) float f32x4;
typedef __attribute__((ext_vector_type(2))) float f32x2;

__device__ __forceinline__ const float* pptr(const float* Pp, int i, int rp) {
  return Pp + ((size_t)(rp >> 7) * NB + i) * 128 + (rp & 127);
}

__device__ __forceinline__ int invperm(int rp) {
  if (rp >= 96 && rp < 2400) {
    int t = rp - 96; int kb = t / 192; int rem = t - kb * 192;
    return 96 + (rem >> 2) * 48 + (kb * 4 + (rem & 3));
  }
  if (rp >= 2448 && rp < 4752) {
    int t = rp - 2448; int kb = t / 192; int rem = t - kb * 192;
    return 2448 + (rem >> 2) * 48 + (kb * 4 + (rem & 3));
  }
  return rp;
}

// ---------------------------------------------------------------------------
// Kernel 1: PERSISTENT split-fp16 MFMA GEMM (byte-identical to R10/R11).
// ~60 us real = write roofline for the 163 MB intermediate; the rest of the
// apparent time is the harness's 159 MB d_ws re-poison inside each replay.
// ---------------------------------------------------------------------------
__global__ __launch_bounds__(256, 2) void hyper_gemm(
    const float* __restrict__ x, const float* __restrict__ c,
    const float* __restrict__ hw1, const float* __restrict__ hb1,
    const float* __restrict__ hw2, const float* __restrict__ hb2,
    float* __restrict__ Pp)
{
  const int t    = threadIdx.x;
  const int lane = t & 63;
  const int wv   = t >> 6;
  const int m16  = lane & 15;
  const int q    = lane >> 4;
  const int rp0  = blockIdx.x * 128;

  const float* wr[2];
  float bias[2];
  #pragma unroll
  for (int nt = 0; nt < 2; ++nt) {
    int rp = rp0 + wv * 32 + nt * 16 + m16;
    int r  = (rp < NP) ? invperm(rp) : 0;
    wr[nt]   = hw2 + (size_t)r * 96;
    bias[nt] = (rp < NP) ? hb2[r] : 0.f;
  }

  f16x8 bh[3][2], bl[3][2];
  #pragma unroll
  for (int ch = 0; ch < 3; ++ch) {
    const int k0 = ch * 32 + q * 8;
    #pragma unroll
    for (int nt = 0; nt < 2; ++nt) {
      float4 f0 = *(const float4*)(wr[nt] + k0);
      float4 f1 = *(const float4*)(wr[nt] + k0 + 4);
      float fv[8] = {f0.x,f0.y,f0.z,f0.w,f1.x,f1.y,f1.z,f1.w};
      #pragma unroll
      for (int e = 0; e < 8; ++e) {
        _Float16 hi = (_Float16)fv[e];
        float r = fv[e] - (float)hi;
        bh[ch][nt][e] = hi;
        bl[ch][nt][e] = (_Float16)r;
      }
    }
  }

  float* cbase = Pp + (size_t)blockIdx.x * NB * 128;

  for (int mtile = blockIdx.y; mtile < 128; mtile += GY) {
    const int i0 = mtile * 64;

    float xv[4], cv[4];
    #pragma unroll
    for (int mt = 0; mt < 4; ++mt) {
      int i = i0 + mt * 16 + m16;
      xv[mt] = x[i]; cv[mt] = c[i];
    }

    f32x4 acc[4][2];
    #pragma unroll
    for (int mt = 0; mt < 4; ++mt)
      #pragma unroll
      for (int nt = 0; nt < 2; ++nt)
        acc[mt][nt] = (f32x4){0.f, 0.f, 0.f, 0.f};

    #pragma unroll
    for (int ch = 0; ch < 3; ++ch) {
      const int k0 = ch * 32 + q * 8;

      float4 A0 = *(const float4*)(hw1 + 2 * k0);
      float4 A1 = *(const float4*)(hw1 + 2 * k0 + 4);
      float4 A2 = *(const float4*)(hw1 + 2 * k0 + 8);
      float4 A3 = *(const float4*)(hw1 + 2 * k0 + 12);
      float4 B0 = *(const float4*)(hb1 + k0);
      float4 B1 = *(const float4*)(hb1 + k0 + 4);
      float w0k[8] = {A0.x,A0.z,A1.x,A1.z,A2.x,A2.z,A3.x,A3.z};
      float w1k[8] = {A0.y,A0.w,A1.y,A1.w,A2.y,A2.w,A3.y,A3.w};
      float bk[8]  = {B0.x,B0.y,B0.z,B0.w,B1.x,B1.y,B1.z,B1.w};

      f16x8 ah[4], al[4];
      #pragma unroll
      for (int mt = 0; mt < 4; ++mt) {
        #pragma unroll
        for (int j = 0; j < 8; ++j) {
          float h = fmaf(xv[mt], w0k[j], fmaf(cv[mt], w1k[j], bk[j]));
          h = h > 0.f ? h : 0.f;
          _Float16 hi = (_Float16)h;
          float r = h - (float)hi;
          ah[mt][j] = hi;
          al[mt][j] = (_Float16)r;
        }
      }

      #pragma unroll
      for (int mt = 0; mt < 4; ++mt)
        #pragma unroll
        for (int nt = 0; nt < 2; ++nt) {
          acc[mt][nt] = __builtin_amdgcn_mfma_f32_16x16x32_f16(al[mt], bl[ch][nt], acc[mt][nt], 0, 0, 0);
          acc[mt][nt] = __builtin_amdgcn_mfma_f32_16x16x32_f16(ah[mt], bl[ch][nt], acc[mt][nt], 0, 0, 0);
          acc[mt][nt] = __builtin_amdgcn_mfma_f32_16x16x32_f16(al[mt], bh[ch][nt], acc[mt][nt], 0, 0, 0);
          acc[mt][nt] = __builtin_amdgcn_mfma_f32_16x16x32_f16(ah[mt], bh[ch][nt], acc[mt][nt], 0, 0, 0);
        }
    }

    #pragma unroll
    for (int nt = 0; nt < 2; ++nt) {
      int off = wv * 32 + nt * 16 + m16;
      if (rp0 + off < NP) {
        #pragma unroll
        for (int mt = 0; mt < 4; ++mt)
          #pragma unroll
          for (int r = 0; r < 4; ++r) {
            int i = i0 + mt * 16 + q * 4 + r;
            cbase[(size_t)i * 128 + off] = acc[mt][nt][r] + bias[nt];
          }
      }
    }
  }
}

// ---------------------------------------------------------------------------
// Kernel 2 (R13): per-item 20-step Adam.
// Register-ledger fix: R11's full ph+pd prefetch = 96 regs -> ~220 total ->
// 1.5-2 waves/SIMD (occ 19%). Now only ph[12] is prefetched (48 regs); the
// dd-leg reads pd inline from LDS (latency covered by the surrounding FMA
// stream). Body ~175 -> launch_bounds(256,3) cap 170 should fit without
// spill (R9 proved (256,3) delivers ~30% occupancy; it only lost to spill).
// Spill tripwire: WRITE_SIZE must stay ~64 B.
// ---------------------------------------------------------------------------
__device__ __forceinline__ float rcp_nr(float d) {
  float r = __builtin_amdgcn_rcpf(d);
  return fmaf(-d, r, 2.f) * r;
}

#define DPP_ADD(x, ctrl, rmask)                                               \
  (x) += __int_as_float(__builtin_amdgcn_update_dpp(                          \
      0, __float_as_int(x), (ctrl), (rmask), 0xf, false))

__global__ __launch_bounds__(256, 3) void adam_inner(
    const float* __restrict__ Pp, float* __restrict__ out)
{
  __shared__ __align__(16) float hd[4][2][96];   // [wave][buf][h(48)|dh(48)]

  const int lane = threadIdx.x & 63;
  const int wv   = threadIdx.x >> 6;
  const int i    = blockIdx.x * 4 + wv;
  const bool act = lane < NW;

  float* buf0 = &hd[wv][0][0];
  float* buf1 = &hd[wv][1][0];

  float w0  = act ? *pptr(Pp, i, lane)        : 0.f;
  float b0  = act ? *pptr(Pp, i, 48 + lane)   : 0.f;
  float b1v = act ? *pptr(Pp, i, 2400 + lane) : 0.f;
  float b2v = act ? *pptr(Pp, i, 4752 + lane) : 0.f;
  float w3  = act ? *pptr(Pp, i, 4800 + lane) : 0.f;

  f32x2 w1p[24], w2p[24];
  #pragma unroll
  for (int kb = 0; kb < 12; ++kb) {
    float4 q1 = *(const float4*)pptr(Pp, i, 96 + kb * 192 + lane * 4);
    w1p[2 * kb]     = (f32x2){q1.x, q1.y};
    w1p[2 * kb + 1] = (f32x2){q1.z, q1.w};
    float4 q2 = *(const float4*)pptr(Pp, i, 2448 + kb * 192 + lane * 4);
    w2p[2 * kb]     = (f32x2){q2.x, q2.y};
    w2p[2 * kb + 1] = (f32x2){q2.z, q2.w};
  }

  float y = 0.f, m = 0.f, v = 0.f;
  float b1t = 1.f, b2t = 1.f;

  #pragma unroll 1
  for (int t = 0; t < 20; ++t) {
    // ---- layer 0 (scalar input): lane j computes unit j ----
    float z  = fmaf(w0, y, b0);
    float e  = fminf(__expf(-z), 8.0e37f);
    float s  = rcp_nr(1.f + e);
    float h  = z * s;
    float dh = fmaf(z * s, 1.f - s, s) * w0;
    if (act) { buf0[lane] = h; buf0[48 + lane] = dh; }

    // ---- layer 1: prefetch ph only (48 regs); pd read inline ----
    float4 ph[12];
    #pragma unroll
    for (int kk = 0; kk < 12; ++kk) ph[kk] = *(const float4*)(buf0 + 4 * kk);
    {
      f32x2 zz[4] = {(f32x2){b1v, 0.f}, (f32x2){0.f, 0.f},
                     (f32x2){0.f, 0.f}, (f32x2){0.f, 0.f}};
      f32x2 dd[4] = {(f32x2){0.f, 0.f}, (f32x2){0.f, 0.f},
                     (f32x2){0.f, 0.f}, (f32x2){0.f, 0.f}};
      #pragma unroll
      for (int kk = 0; kk < 12; ++kk) {
        int c0 = (2 * kk) & 3, c1 = (2 * kk + 1) & 3;
        float4 pd = *(const float4*)(buf0 + 48 + 4 * kk);   // inline LDS read
        zz[c0] = __builtin_elementwise_fma(w1p[2 * kk],     (f32x2){ph[kk].x, ph[kk].y}, zz[c0]);
        zz[c1] = __builtin_elementwise_fma(w1p[2 * kk + 1], (f32x2){ph[kk].z, ph[kk].w}, zz[c1]);
        dd[c0] = __builtin_elementwise_fma(w1p[2 * kk],     (f32x2){pd.x, pd.y}, dd[c0]);
        dd[c1] = __builtin_elementwise_fma(w1p[2 * kk + 1], (f32x2){pd.z, pd.w}, dd[c1]);
      }
      f32x2 zs = (zz[0] + zz[1]) + (zz[2] + zz[3]);
      f32x2 ds = (dd[0] + dd[1]) + (dd[2] + dd[3]);
      float z1  = zs.x + zs.y;
      float dz1 = ds.x + ds.y;

      e  = fminf(__expf(-z1), 8.0e37f);
      s  = rcp_nr(1.f + e);
      h  = z1 * s;
      dh = fmaf(z1 * s, 1.f - s, s) * dz1;
    }
    if (act) { buf1[lane] = h; buf1[48 + lane] = dh; }

    // ---- layer 2 ----
    #pragma unroll
    for (int kk = 0; kk < 12; ++kk) ph[kk] = *(const float4*)(buf1 + 4 * kk);
    {
      f32x2 zz[4] = {(f32x2){b2v, 0.f}, (f32x2){0.f, 0.f},
                     (f32x2){0.f, 0.f}, (f32x2){0.f, 0.f}};
      f32x2 dd[4] = {(f32x2){0.f, 0.f}, (f32x2){0.f, 0.f},
                     (f32x2){0.f, 0.f}, (f32x2){0.f, 0.f}};
      #pragma unroll
      for (int kk = 0; kk < 12; ++kk) {
        int c0 = (2 * kk) & 3, c1 = (2 * kk + 1) & 3;
        float4 pd = *(const float4*)(buf1 + 48 + 4 * kk);   // inline LDS read
        zz[c0] = __builtin_elementwise_fma(w2p[2 * kk],     (f32x2){ph[kk].x, ph[kk].y}, zz[c0]);
        zz[c1] = __builtin_elementwise_fma(w2p[2 * kk + 1], (f32x2){ph[kk].z, ph[kk].w}, zz[c1]);
        dd[c0] = __builtin_elementwise_fma(w2p[2 * kk],     (f32x2){pd.x, pd.y}, dd[c0]);
        dd[c1] = __builtin_elementwise_fma(w2p[2 * kk + 1], (f32x2){pd.z, pd.w}, dd[c1]);
      }
      f32x2 zs = (zz[0] + zz[1]) + (zz[2] + zz[3]);
      f32x2 ds = (dd[0] + dd[1]) + (dd[2] + dd[3]);
      float z2  = zs.x + zs.y;
      float dz2 = ds.x + ds.y;

      e  = fminf(__expf(-z2), 8.0e37f);
      s  = rcp_nr(1.f + e);
      dh = fmaf(z2 * s, 1.f - s, s) * dz2;
    }

    // ---- g = w3 . dh3 : DPP reduction (VALU pipe, no DS ops) ----
    float r = act ? w3 * dh : 0.f;
    DPP_ADD(r, 0x111, 0xf);   // row_shr:1
    DPP_ADD(r, 0x112, 0xf);   // row_shr:2
    DPP_ADD(r, 0x114, 0xf);   // row_shr:4
    DPP_ADD(r, 0x118, 0xf);   // row_shr:8  -> lane15 of each row = row sum
    DPP_ADD(r, 0x142, 0xa);   // row_bcast:15 into rows 1,3
    DPP_ADD(r, 0x143, 0xc);   // row_bcast:31 into rows 2,3 -> lane63 = total
    float g = __int_as_float(__builtin_amdgcn_readlane(__float_as_int(r), 63));

    // ---- Adam update (replicated per lane) ----
    m = fmaf(0.9f,   m, 0.1f   * g);
    v = fmaf(0.999f, v, 0.001f * g * g);
    b1t *= 0.9f; b2t *= 0.999f;
    float mh  = m * rcp_nr(1.f - b1t);
    float vh  = v * rcp_nr(1.f - b2t);
    float den = __builtin_amdgcn_sqrtf(vh) + 1e-8f;
    y -= 0.1f * mh * rcp_nr(den);
  }

  if (lane == 0) out[i] = y;
}

// ---------------------------------------------------------------------------
extern "C" void kernel_launch(void* const* d_in, const int* in_sizes, int n_in,
                              void* d_out, int out_size, void* d_ws, size_t ws_size,
                              hipStream_t stream) {
  const float* x   = (const float*)d_in[0];
  const float* c   = (const float*)d_in[1];
  const float* hw1 = (const float*)d_in[2];
  const float* hb1 = (const float*)d_in[3];
  const float* hw2 = (const float*)d_in[4];
  const float* hb2 = (const float*)d_in[5];
  float* Pp  = (float*)d_ws;   // NCH*NB*128*4 = 159,383,552 bytes
  float* out = (float*)d_out;

  dim3 gridB(NCH, GY);         // 38 x 16 persistent blocks
  hyper_gemm<<<gridB, dim3(256), 0, stream>>>(x, c, hw1, hb1, hw2, hb2, Pp);
  adam_inner<<<dim3(2048), dim3(256), 0, stream>>>(Pp, out);
}

// Round 15
// 222.438 us; speedup vs baseline: 2.5033x; 1.0687x over previous
//
#include <hip/hip_runtime.h>
#include <cstdint>
#include <cstddef>

// Problem constants
#define NB    8192      // batch
#define NP    4849      // params per item
#define NW    48        // target net width
#define NCH   38        // ceil(NP/128)
#define GY    16        // persistent-gemm grid y; each block does 128/GY = 8 M-tiles

// Tiled intermediate layout: addr(i, rp) = ((rp>>7)*NB + i)*128 + (rp&127)
typedef __attribute__((ext_vector_type(8))) _Float16 f16x8;
typedef __attribute__((ext_vector_type(4))) float f32x4;
typedef __attribute__((ext_vector_type(2))) float f32x2;

__device__ __forceinline__ const float* pptr(const float* Pp, int i, int rp) {
  return Pp + ((size_t)(rp >> 7) * NB + i) * 128 + (rp & 127);
}

// invperm maps 4-aligned quads of rp to 4 CONSECUTIVE original indices
// (within each region; all region boundaries are multiples of 4).
__device__ __forceinline__ int invperm(int rp) {
  if (rp >= 96 && rp < 2400) {
    int t = rp - 96; int kb = t / 192; int rem = t - kb * 192;
    return 96 + (rem >> 2) * 48 + (kb * 4 + (rem & 3));
  }
  if (rp >= 2448 && rp < 4752) {
    int t = rp - 2448; int kb = t / 192; int rem = t - kb * 192;
    return 2448 + (rem >> 2) * 48 + (kb * 4 + (rem & 3));
  }
  return rp;
}

// ---------------------------------------------------------------------------
// Kernel 1 (R15 = R14 fixed): persistent split-fp16 MFMA GEMM with
// OPERAND-SWAPPED mfma: D[m=param][n=item] = W x H. The C-layout
// row=quad*4+reg indexes 4 CONSECUTIVE params per lane -> epilogue is ONE
// ext-vector f32x4 nontemporal store per fragment (dwordx4; 4x fewer store
// instrs than the scalar-dword epilogue used by every prior variant).
// R14's only failure was __builtin_nontemporal_store rejecting HIP float4;
// fixed by using the clang ext_vector type.
// ---------------------------------------------------------------------------
__global__ __launch_bounds__(256, 2) void hyper_gemm(
    const float* __restrict__ x, const float* __restrict__ c,
    const float* __restrict__ hw1, const float* __restrict__ hb1,
    const float* __restrict__ hw2, const float* __restrict__ hb2,
    float* __restrict__ Pp)
{
  const int t    = threadIdx.x;
  const int lane = t & 63;
  const int wv   = t >> 6;
  const int m16  = lane & 15;
  const int q    = lane >> 4;
  const int rp0  = blockIdx.x * 128;

  // ---- W fragments (A-operand): lane&15 = param row within tile ----
  const float* wr[2];
  f32x4 biasv[2];
  #pragma unroll
  for (int pt = 0; pt < 2; ++pt) {
    int rp = rp0 + wv * 32 + pt * 16 + m16;          // row for W fragment
    int r  = (rp < NP) ? invperm(rp) : 0;
    wr[pt] = hw2 + (size_t)r * 96;

    // bias quad for this lane's 4 consecutive params (epilogue)
    int rpb = rp0 + wv * 32 + pt * 16 + q * 4;
    if (rpb + 3 < NP) {
      const float* bp = hb2 + invperm(rpb);
      biasv[pt] = (f32x4){bp[0], bp[1], bp[2], bp[3]};
    } else {
      float b0 = (rpb     < NP) ? hb2[invperm(rpb)]     : 0.f;
      float b1 = (rpb + 1 < NP) ? hb2[invperm(rpb + 1)] : 0.f;
      float b2 = (rpb + 2 < NP) ? hb2[invperm(rpb + 2)] : 0.f;
      float b3 = (rpb + 3 < NP) ? hb2[invperm(rpb + 3)] : 0.f;
      biasv[pt] = (f32x4){b0, b1, b2, b3};
    }
  }

  f16x8 wh[3][2], wl[3][2];
  #pragma unroll
  for (int ch = 0; ch < 3; ++ch) {
    const int k0 = ch * 32 + q * 8;
    #pragma unroll
    for (int pt = 0; pt < 2; ++pt) {
      float4 f0 = *(const float4*)(wr[pt] + k0);
      float4 f1 = *(const float4*)(wr[pt] + k0 + 4);
      float fv[8] = {f0.x,f0.y,f0.z,f0.w,f1.x,f1.y,f1.z,f1.w};
      #pragma unroll
      for (int e = 0; e < 8; ++e) {
        _Float16 hi = (_Float16)fv[e];
        float r = fv[e] - (float)hi;
        wh[ch][pt][e] = hi;
        wl[ch][pt][e] = (_Float16)r;
      }
    }
  }

  float* cbase = Pp + (size_t)blockIdx.x * NB * 128;

  for (int mtile = blockIdx.y; mtile < 128; mtile += GY) {
    const int i0 = mtile * 64;

    float xv[4], cv[4];
    #pragma unroll
    for (int it = 0; it < 4; ++it) {
      int i = i0 + it * 16 + m16;
      xv[it] = x[i]; cv[it] = c[i];
    }

    f32x4 acc[2][4];   // [param-tile][item-tile]
    #pragma unroll
    for (int pt = 0; pt < 2; ++pt)
      #pragma unroll
      for (int it = 0; it < 4; ++it)
        acc[pt][it] = (f32x4){0.f, 0.f, 0.f, 0.f};

    #pragma unroll
    for (int ch = 0; ch < 3; ++ch) {
      const int k0 = ch * 32 + q * 8;

      float4 A0 = *(const float4*)(hw1 + 2 * k0);
      float4 A1 = *(const float4*)(hw1 + 2 * k0 + 4);
      float4 A2 = *(const float4*)(hw1 + 2 * k0 + 8);
      float4 A3 = *(const float4*)(hw1 + 2 * k0 + 12);
      float4 B0 = *(const float4*)(hb1 + k0);
      float4 B1 = *(const float4*)(hb1 + k0 + 4);
      float w0k[8] = {A0.x,A0.z,A1.x,A1.z,A2.x,A2.z,A3.x,A3.z};
      float w1k[8] = {A0.y,A0.w,A1.y,A1.w,A2.y,A2.w,A3.y,A3.w};
      float bk[8]  = {B0.x,B0.y,B0.z,B0.w,B1.x,B1.y,B1.z,B1.w};

      // H fragments (B-operand): lane&15 = item, k = quad*8+j
      f16x8 hh[4], hl[4];
      #pragma unroll
      for (int it = 0; it < 4; ++it) {
        #pragma unroll
        for (int j = 0; j < 8; ++j) {
          float h = fmaf(xv[it], w0k[j], fmaf(cv[it], w1k[j], bk[j]));
          h = h > 0.f ? h : 0.f;
          _Float16 hi = (_Float16)h;
          float r = h - (float)hi;
          hh[it][j] = hi;
          hl[it][j] = (_Float16)r;
        }
      }

      #pragma unroll
      for (int pt = 0; pt < 2; ++pt)
        #pragma unroll
        for (int it = 0; it < 4; ++it) {
          acc[pt][it] = __builtin_amdgcn_mfma_f32_16x16x32_f16(wl[ch][pt], hl[it], acc[pt][it], 0, 0, 0);
          acc[pt][it] = __builtin_amdgcn_mfma_f32_16x16x32_f16(wh[ch][pt], hl[it], acc[pt][it], 0, 0, 0);
          acc[pt][it] = __builtin_amdgcn_mfma_f32_16x16x32_f16(wl[ch][pt], hh[it], acc[pt][it], 0, 0, 0);
          acc[pt][it] = __builtin_amdgcn_mfma_f32_16x16x32_f16(wh[ch][pt], hh[it], acc[pt][it], 0, 0, 0);
        }
    }

    // ---- epilogue: bias + ONE f32x4 NT store per fragment ----
    #pragma unroll
    for (int pt = 0; pt < 2; ++pt) {
      int offb = wv * 32 + pt * 16 + q * 4;     // 4 consecutive params
      int rpb  = rp0 + offb;
      if (rpb + 3 < NP) {
        #pragma unroll
        for (int it = 0; it < 4; ++it) {
          int i = i0 + it * 16 + m16;
          f32x4 v = acc[pt][it] + biasv[pt];
          __builtin_nontemporal_store(v, (f32x4*)(cbase + (size_t)i * 128 + offb));
        }
      } else {
        #pragma unroll
        for (int it = 0; it < 4; ++it) {
          int i = i0 + it * 16 + m16;
          #pragma unroll
          for (int r = 0; r < 4; ++r)
            if (rpb + r < NP)
              cbase[(size_t)i * 128 + offb + r] = acc[pt][it][r] + biasv[pt][r];
        }
      }
    }
  }
}

// ---------------------------------------------------------------------------
// Kernel 2: per-item 20-step Adam — EXACT R11 config (103 us measured):
// (256,2), full ph+pd prefetch, pk_fma chains, DPP reduction. R9/R13 proved
// every attempt to cap regs below this spills (WRITE_SIZE balloons).
// ---------------------------------------------------------------------------
__device__ __forceinline__ float rcp_nr(float d) {
  float r = __builtin_amdgcn_rcpf(d);
  return fmaf(-d, r, 2.f) * r;
}

#define DPP_ADD(x, ctrl, rmask)                                               \
  (x) += __int_as_float(__builtin_amdgcn_update_dpp(                          \
      0, __float_as_int(x), (ctrl), (rmask), 0xf, false))

__global__ __launch_bounds__(256, 2) void adam_inner(
    const float* __restrict__ Pp, float* __restrict__ out)
{
  __shared__ __align__(16) float hd[4][2][96];   // [wave][buf][h(48)|dh(48)]

  const int lane = threadIdx.x & 63;
  const int wv   = threadIdx.x >> 6;
  const int i    = blockIdx.x * 4 + wv;
  const bool act = lane < NW;

  float* buf0 = &hd[wv][0][0];
  float* buf1 = &hd[wv][1][0];

  float w0  = act ? *pptr(Pp, i, lane)        : 0.f;
  float b0  = act ? *pptr(Pp, i, 48 + lane)   : 0.f;
  float b1v = act ? *pptr(Pp, i, 2400 + lane) : 0.f;
  float b2v = act ? *pptr(Pp, i, 4752 + lane) : 0.f;
  float w3  = act ? *pptr(Pp, i, 4800 + lane) : 0.f;

  f32x2 w1p[24], w2p[24];
  #pragma unroll
  for (int kb = 0; kb < 12; ++kb) {
    float4 q1 = *(const float4*)pptr(Pp, i, 96 + kb * 192 + lane * 4);
    w1p[2 * kb]     = (f32x2){q1.x, q1.y};
    w1p[2 * kb + 1] = (f32x2){q1.z, q1.w};
    float4 q2 = *(const float4*)pptr(Pp, i, 2448 + kb * 192 + lane * 4);
    w2p[2 * kb]     = (f32x2){q2.x, q2.y};
    w2p[2 * kb + 1] = (f32x2){q2.z, q2.w};
  }

  float y = 0.f, m = 0.f, v = 0.f;
  float b1t = 1.f, b2t = 1.f;

  #pragma unroll 1
  for (int t = 0; t < 20; ++t) {
    // ---- layer 0 (scalar input): lane j computes unit j ----
    float z  = fmaf(w0, y, b0);
    float e  = fminf(__expf(-z), 8.0e37f);
    float s  = rcp_nr(1.f + e);
    float h  = z * s;
    float dh = fmaf(z * s, 1.f - s, s) * w0;
    if (act) { buf0[lane] = h; buf0[48 + lane] = dh; }

    // ---- layer 1: prefetch all broadcast reads, then indep pk chains ----
    float4 ph[12], pd[12];
    #pragma unroll
    for (int kk = 0; kk < 12; ++kk) {
      ph[kk] = *(const float4*)(buf0 + 4 * kk);
      pd[kk] = *(const float4*)(buf0 + 48 + 4 * kk);
    }
    {
      f32x2 zz[4] = {(f32x2){b1v, 0.f}, (f32x2){0.f, 0.f},
                     (f32x2){0.f, 0.f}, (f32x2){0.f, 0.f}};
      f32x2 dd[4] = {(f32x2){0.f, 0.f}, (f32x2){0.f, 0.f},
                     (f32x2){0.f, 0.f}, (f32x2){0.f, 0.f}};
      #pragma unroll
      for (int kk = 0; kk < 12; ++kk) {
        int c0 = (2 * kk) & 3, c1 = (2 * kk + 1) & 3;
        zz[c0] = __builtin_elementwise_fma(w1p[2 * kk],     (f32x2){ph[kk].x, ph[kk].y}, zz[c0]);
        zz[c1] = __builtin_elementwise_fma(w1p[2 * kk + 1], (f32x2){ph[kk].z, ph[kk].w}, zz[c1]);
        dd[c0] = __builtin_elementwise_fma(w1p[2 * kk],     (f32x2){pd[kk].x, pd[kk].y}, dd[c0]);
        dd[c1] = __builtin_elementwise_fma(w1p[2 * kk + 1], (f32x2){pd[kk].z, pd[kk].w}, dd[c1]);
      }
      f32x2 zs = (zz[0] + zz[1]) + (zz[2] + zz[3]);
      f32x2 ds = (dd[0] + dd[1]) + (dd[2] + dd[3]);
      float z1  = zs.x + zs.y;
      float dz1 = ds.x + ds.y;

      e  = fminf(__expf(-z1), 8.0e37f);
      s  = rcp_nr(1.f + e);
      h  = z1 * s;
      dh = fmaf(z1 * s, 1.f - s, s) * dz1;
    }
    if (act) { buf1[lane] = h; buf1[48 + lane] = dh; }

    // ---- layer 2 ----
    #pragma unroll
    for (int kk = 0; kk < 12; ++kk) {
      ph[kk] = *(const float4*)(buf1 + 4 * kk);
      pd[kk] = *(const float4*)(buf1 + 48 + 4 * kk);
    }
    {
      f32x2 zz[4] = {(f32x2){b2v, 0.f}, (f32x2){0.f, 0.f},
                     (f32x2){0.f, 0.f}, (f32x2){0.f, 0.f}};
      f32x2 dd[4] = {(f32x2){0.f, 0.f}, (f32x2){0.f, 0.f},
                     (f32x2){0.f, 0.f}, (f32x2){0.f, 0.f}};
      #pragma unroll
      for (int kk = 0; kk < 12; ++kk) {
        int c0 = (2 * kk) & 3, c1 = (2 * kk + 1) & 3;
        zz[c0] = __builtin_elementwise_fma(w2p[2 * kk],     (f32x2){ph[kk].x, ph[kk].y}, zz[c0]);
        zz[c1] = __builtin_elementwise_fma(w2p[2 * kk + 1], (f32x2){ph[kk].z, ph[kk].w}, zz[c1]);
        dd[c0] = __builtin_elementwise_fma(w2p[2 * kk],     (f32x2){pd[kk].x, pd[kk].y}, dd[c0]);
        dd[c1] = __builtin_elementwise_fma(w2p[2 * kk + 1], (f32x2){pd[kk].z, pd[kk].w}, dd[c1]);
      }
      f32x2 zs = (zz[0] + zz[1]) + (zz[2] + zz[3]);
      f32x2 ds = (dd[0] + dd[1]) + (dd[2] + dd[3]);
      float z2  = zs.x + zs.y;
      float dz2 = ds.x + ds.y;

      e  = fminf(__expf(-z2), 8.0e37f);
      s  = rcp_nr(1.f + e);
      dh = fmaf(z2 * s, 1.f - s, s) * dz2;
    }

    // ---- g = w3 . dh3 : DPP reduction (VALU pipe, no DS ops) ----
    float r = act ? w3 * dh : 0.f;
    DPP_ADD(r, 0x111, 0xf);   // row_shr:1
    DPP_ADD(r, 0x112, 0xf);   // row_shr:2
    DPP_ADD(r, 0x114, 0xf);   // row_shr:4
    DPP_ADD(r, 0x118, 0xf);   // row_shr:8  -> lane15 of each row = row sum
    DPP_ADD(r, 0x142, 0xa);   // row_bcast:15 into rows 1,3
    DPP_ADD(r, 0x143, 0xc);   // row_bcast:31 into rows 2,3 -> lane63 = total
    float g = __int_as_float(__builtin_amdgcn_readlane(__float_as_int(r), 63));

    // ---- Adam update (replicated per lane) ----
    m = fmaf(0.9f,   m, 0.1f   * g);
    v = fmaf(0.999f, v, 0.001f * g * g);
    b1t *= 0.9f; b2t *= 0.999f;
    float mh  = m * rcp_nr(1.f - b1t);
    float vh  = v * rcp_nr(1.f - b2t);
    float den = __builtin_amdgcn_sqrtf(vh) + 1e-8f;
    y -= 0.1f * mh * rcp_nr(den);
  }

  if (lane == 0) out[i] = y;
}

// ---------------------------------------------------------------------------
extern "C" void kernel_launch(void* const* d_in, const int* in_sizes, int n_in,
                              void* d_out, int out_size, void* d_ws, size_t ws_size,
                              hipStream_t stream) {
  const float* x   = (const float*)d_in[0];
  const float* c   = (const float*)d_in[1];
  const float* hw1 = (const float*)d_in[2];
  const float* hb1 = (const float*)d_in[3];
  const float* hw2 = (const float*)d_in[4];
  const float* hb2 = (const float*)d_in[5];
  float* Pp  = (float*)d_ws;   // NCH*NB*128*4 = 159,383,552 bytes
  float* out = (float*)d_out;

  dim3 gridB(NCH, GY);         // 38 x 16 persistent blocks
  hyper_gemm<<<gridB, dim3(256), 0, stream>>>(x, c, hw1, hb1, hw2, hb2, Pp);
  adam_inner<<<dim3(2048), dim3(256), 0, stream>>>(Pp, out);
}